// Round 3
// 609.988 us; speedup vs baseline: 1.1069x; 1.1069x over previous
//
#include <hip/hip_runtime.h>

// MirrorAttention on MI355X (gfx950). Round 7: back to the R4-verified kernel
// set (675us PASS), attacking the measured bottleneck (PV gemm: 92us, 576
// blocks = 2.25/CU, Occ 20%, MfmaUtil 4.5% -> latency-bound) with minimal
// verbatim-body deltas:
//   (1) split-K PV: grid (36,2,24) = 1728 blocks, 3 K-slices of 768, fp32
//       atomicAdd into zeroed omidF; final reads omidF via the VERIFIED BF32
//       staging template path (gemm_kernel<false,3,true,true,false>).
//   (2) proj fusion: 5 launches -> proj4 (z=32, verbatim body + ptr switch)
//       + deferred fh proj (verbatim template call) so fv/omidF/fh time-share
//       one scratch region. ws total 109.5MB < proven 114.19MB.
// Score gemm, softmax_stats, fold, fallback: byte-for-byte R4.

typedef __attribute__((ext_vector_type(8))) short short8;
typedef __attribute__((ext_vector_type(4))) short short4_t;
typedef __attribute__((ext_vector_type(8))) __bf16 bf16x8;
typedef __attribute__((ext_vector_type(4))) float f32x4;

#define DEV __device__ __forceinline__

constexpr int BB = 8, CC = 512, MID = 128, NB = 2304;
constexpr float ATT_SCALE = 0.08838834764831845f;   // 128^-0.5
constexpr float RSQ = 0.9999950000374998f;          // 1/sqrt(1+1e-5)

DEV float bf2f(unsigned short u) {
    unsigned int x = ((unsigned int)u) << 16;
    return __builtin_bit_cast(float, x);
}
DEV unsigned short f2bf(float f) {   // round-to-nearest-even
    unsigned int x = __builtin_bit_cast(unsigned int, f);
    x += 0x7fffu + ((x >> 16) & 1u);
    return (unsigned short)(x >> 16);
}
DEV bf16x8 ldfrag(const unsigned short* p) {
    return __builtin_bit_cast(bf16x8, *(const short8*)p);
}

// ---------------------------------------------------------------------------
// fold kernel: fp32 weights -> bf16 ws copies (BN folded), biases -> f32.
// (R4 verbatim)
__global__ __launch_bounds__(256)
void fold_kernel(const float* __restrict__ Wa, const float* __restrict__ ba,
                 const float* __restrict__ ga, const float* __restrict__ ta,
                 const float* __restrict__ Wv, const float* __restrict__ bv,
                 const float* __restrict__ gv, const float* __restrict__ tv,
                 const float* __restrict__ Wgav, const float* __restrict__ bgav,
                 const float* __restrict__ Wgah, const float* __restrict__ bgah,
                 const float* __restrict__ Wfav, const float* __restrict__ bfav,
                 const float* __restrict__ Wfah, const float* __restrict__ bfah,
                 unsigned short* __restrict__ WaE, unsigned short* __restrict__ WvE,
                 unsigned short* __restrict__ WgavE, unsigned short* __restrict__ WgahE,
                 unsigned short* __restrict__ WfavE, unsigned short* __restrict__ WfahE,
                 float* __restrict__ biases)
{
    int idx = blockIdx.x * 256 + threadIdx.x;
    if (idx < 65536) {
        int m = idx >> 9;                  // row of [128][512]
        WaE[idx]   = f2bf(ga[m] * RSQ * Wa[idx]);
        WvE[idx]   = f2bf(gv[m] * RSQ * Wv[idx]);
        WgavE[idx] = f2bf(Wgav[idx]);
        WgahE[idx] = f2bf(Wgah[idx]);
        WfavE[idx] = f2bf(Wfav[idx]);      // [512][128] flat, same 65536 count
        WfahE[idx] = f2bf(Wfah[idx]);
    }
    if (idx < 128) {
        biases[idx]       = ba[idx] * ga[idx] * RSQ + ta[idx];
        biases[128 + idx] = bv[idx] * gv[idx] * RSQ + tv[idx];
        biases[256 + idx] = bgav[idx];
        biases[384 + idx] = bgah[idx];
    }
    if (idx < 512) {
        biases[512 + idx]  = bfav[idx];
        biases[1024 + idx] = bfah[idx];
    }
}

// ---------------------------------------------------------------------------
// Generic MFMA GEMM (R4 verbatim): OUT[m,n] = epilogue( sum_k A[m,k]*B[k,n] )
template<bool AT, int EPI, bool BF32, bool OF32, bool EXPB>
__global__ __launch_bounds__(256)
void gemm_kernel(const unsigned short* __restrict__ A, long sAb,
                 const void* __restrict__ Bm, long sBb,
                 void* __restrict__ Out, long sOb,
                 const float* __restrict__ bias,
                 const float* __restrict__ resid, long sRb,
                 const float* __restrict__ stats,
                 int Mdim, int Kdim, int Ndim, float outscale)
{
    constexpr int TM = 64, TN = 64, TK = 32, LD = TK + 8;
    __shared__ unsigned short As[TM * LD];
    __shared__ unsigned short Bs[TN * LD];

    const int tid  = threadIdx.x;
    const int lane = tid & 63;
    const int wave = tid >> 6;
    const int wm = wave >> 1, wn = wave & 1;
    const int m0 = blockIdx.y * TM, n0 = blockIdx.x * TN;
    const int z  = blockIdx.z;

    const unsigned short* Ab = A + (long)z * sAb;

    f32x4 acc[2][2] = {};

    const int ar = tid >> 2, ac = (tid & 3) * 8;   // row-major A staging
    const int tk = tid >> 3, tq = (tid & 7) * 8;   // K-major (transpose) staging
    const int lm = lane & 15, kq = (lane >> 4) * 8;

    for (int k0 = 0; k0 < Kdim; k0 += TK) {
        if constexpr (!AT) {
            short8 v = *(const short8*)(Ab + (long)(m0 + ar) * Kdim + (k0 + ac));
            *(short8*)(&As[ar * LD + ac]) = v;
        } else {
            short8 v = *(const short8*)(Ab + (long)(k0 + tk) * Mdim + (m0 + tq));
            #pragma unroll
            for (int i = 0; i < 8; i++) As[(tq + i) * LD + tk] = (unsigned short)v[i];
        }
        if constexpr (BF32) {
            const float* Bf = (const float*)Bm + (long)z * sBb;
            f32x4 a0 = *(const f32x4*)(Bf + (long)(k0 + tk) * Ndim + (n0 + tq));
            f32x4 a1 = *(const f32x4*)(Bf + (long)(k0 + tk) * Ndim + (n0 + tq) + 4);
            #pragma unroll
            for (int i = 0; i < 4; i++) Bs[(tq + i) * LD + tk]     = f2bf(a0[i]);
            #pragma unroll
            for (int i = 0; i < 4; i++) Bs[(tq + 4 + i) * LD + tk] = f2bf(a1[i]);
        } else {
            const unsigned short* Bu = (const unsigned short*)Bm + (long)z * sBb;
            short8 v = *(const short8*)(Bu + (long)(k0 + tk) * Ndim + (n0 + tq));
            if constexpr (EXPB) {
                const long krow = (long)z * NB + (k0 + tk);
                const float mrow = stats[2 * krow];
                const float rinv = stats[2 * krow + 1];
                #pragma unroll
                for (int i = 0; i < 8; i++)
                    Bs[(tq + i) * LD + tk] =
                        f2bf(__expf(bf2f((unsigned short)v[i]) - mrow) * rinv);
            } else {
                #pragma unroll
                for (int i = 0; i < 8; i++) Bs[(tq + i) * LD + tk] = (unsigned short)v[i];
            }
        }
        __syncthreads();

        bf16x8 afr[2], bfr[2];
        afr[0] = __builtin_bit_cast(bf16x8, *(const short8*)(&As[(wm * 32 + lm) * LD + kq]));
        afr[1] = __builtin_bit_cast(bf16x8, *(const short8*)(&As[(wm * 32 + 16 + lm) * LD + kq]));
        bfr[0] = __builtin_bit_cast(bf16x8, *(const short8*)(&Bs[(wn * 32 + lm) * LD + kq]));
        bfr[1] = __builtin_bit_cast(bf16x8, *(const short8*)(&Bs[(wn * 32 + 16 + lm) * LD + kq]));
        #pragma unroll
        for (int i = 0; i < 2; i++)
            #pragma unroll
            for (int j = 0; j < 2; j++)
                acc[i][j] = __builtin_amdgcn_mfma_f32_16x16x32_bf16(afr[i], bfr[j], acc[i][j], 0, 0, 0);
        __syncthreads();
    }

    const float* Rb = nullptr;
    if constexpr (EPI == 3) Rb = resid + (long)z * sRb;

    const int col = lane & 15, rb = (lane >> 4) * 4;
    #pragma unroll
    for (int i = 0; i < 2; i++) {
        #pragma unroll
        for (int j = 0; j < 2; j++) {
            const int mB = m0 + wm * 32 + i * 16 + rb;
            const int on = n0 + wn * 32 + j * 16 + col;
            #pragma unroll
            for (int r = 0; r < 4; r++) {
                const int m = mB + r;
                float v = acc[i][j][r];
                if constexpr (EPI == 0) {
                    v *= outscale;
                } else {
                    v += bias[m];
                    if constexpr (EPI == 1) v = fmaxf(v, 0.0f);
                    if constexpr (EPI == 3) v += Rb[(long)m * Ndim + on];
                }
                if constexpr (OF32) {
                    float* Of = (float*)Out + (long)z * sOb;
                    Of[(long)m * Ndim + on] = v;
                } else {
                    unsigned short* Ou = (unsigned short*)Out + (long)z * sOb;
                    Ou[(long)m * Ndim + on] = f2bf(v);
                }
            }
        }
    }
}

// ---------------------------------------------------------------------------
// proj4: four 1x1 projections fused (verbatim gemm body, BF32 staging, runtime
// relu flag + pointer switch). grid (36, 2, 8*ncls): cls = z>>3, b = z&7.
__global__ __launch_bounds__(256)
void proj4_kernel(const unsigned short* __restrict__ W0, const unsigned short* __restrict__ W1,
                  const unsigned short* __restrict__ W2, const unsigned short* __restrict__ W3,
                  const float* __restrict__ b0, const float* __restrict__ b1,
                  const float* __restrict__ b2, const float* __restrict__ b3,
                  const float* __restrict__ S0, const float* __restrict__ S1,
                  const float* __restrict__ S2, const float* __restrict__ S3,
                  unsigned short* __restrict__ D0, unsigned short* __restrict__ D1,
                  unsigned short* __restrict__ D2, unsigned short* __restrict__ D3,
                  int reluMask)
{
    constexpr int TK = 32, LD = TK + 8;
    const long sF = (long)MID * NB, sX = (long)CC * NB;
    const int zz = blockIdx.z, cls = zz >> 3, b = zz & 7;
    const unsigned short* W = cls == 0 ? W0 : cls == 1 ? W1 : cls == 2 ? W2 : W3;
    const float* bi = cls == 0 ? b0 : cls == 1 ? b1 : cls == 2 ? b2 : b3;
    const float* Bf = (cls == 0 ? S0 : cls == 1 ? S1 : cls == 2 ? S2 : S3) + (long)b * sX;
    unsigned short* outp = (cls == 0 ? D0 : cls == 1 ? D1 : cls == 2 ? D2 : D3) + (long)b * sF;
    const bool relu = (reluMask >> cls) & 1;

    __shared__ unsigned short As[64 * LD];
    __shared__ unsigned short Bs[64 * LD];

    const int tid = threadIdx.x, lane = tid & 63, wave = tid >> 6;
    const int wm = wave >> 1, wn = wave & 1;
    const int m0 = blockIdx.y * 64, n0 = blockIdx.x * 64;
    const int ar = tid >> 2, ac = (tid & 3) * 8;
    const int tk = tid >> 3, tq = (tid & 7) * 8;
    const int lm = lane & 15, kq = (lane >> 4) * 8;

    f32x4 acc[2][2] = {};
    for (int k0 = 0; k0 < CC; k0 += TK) {
        // A: bf16 weight [128][512], row-major staging (verbatim !AT path)
        short8 v = *(const short8*)(W + (long)(m0 + ar) * CC + (k0 + ac));
        *(short8*)(&As[ar * LD + ac]) = v;
        // B: fp32 x, transpose staging (verbatim BF32 path)
        f32x4 a0 = *(const f32x4*)(Bf + (long)(k0 + tk) * NB + (n0 + tq));
        f32x4 a1 = *(const f32x4*)(Bf + (long)(k0 + tk) * NB + (n0 + tq) + 4);
        #pragma unroll
        for (int i = 0; i < 4; i++) Bs[(tq + i) * LD + tk]     = f2bf(a0[i]);
        #pragma unroll
        for (int i = 0; i < 4; i++) Bs[(tq + 4 + i) * LD + tk] = f2bf(a1[i]);
        __syncthreads();
        bf16x8 afr[2], bfr[2];
        afr[0] = ldfrag(&As[(wm * 32 + lm) * LD + kq]);
        afr[1] = ldfrag(&As[(wm * 32 + 16 + lm) * LD + kq]);
        bfr[0] = ldfrag(&Bs[(wn * 32 + lm) * LD + kq]);
        bfr[1] = ldfrag(&Bs[(wn * 32 + 16 + lm) * LD + kq]);
        #pragma unroll
        for (int i = 0; i < 2; i++)
            #pragma unroll
            for (int j = 0; j < 2; j++)
                acc[i][j] = __builtin_amdgcn_mfma_f32_16x16x32_bf16(afr[i], bfr[j], acc[i][j], 0, 0, 0);
        __syncthreads();
    }

    const int col = lane & 15, rb = (lane >> 4) * 4;
    #pragma unroll
    for (int i = 0; i < 2; i++) {
        #pragma unroll
        for (int j = 0; j < 2; j++) {
            const int mB = m0 + wm * 32 + i * 16 + rb;
            const int on = n0 + wn * 32 + j * 16 + col;
            #pragma unroll
            for (int r = 0; r < 4; r++) {
                const int m = mB + r;
                float v = acc[i][j][r] + bi[m];
                if (relu) v = fmaxf(v, 0.0f);
                outp[(long)m * NB + on] = f2bf(v);
            }
        }
    }
}

// ---------------------------------------------------------------------------
// pv_splitk: omidF[m,j] += sum_{k in slice} g[m,k]*exp(P[k,j]-m_k)*rinv_k.
// Verbatim gemm<false,0,bf16,EXPB> body; deltas: K-slice loop bounds + fp32
// atomicAdd epilogue. grid (36, 2, 24): zb = z/3 batch, zs = z%3 slice.
__global__ __launch_bounds__(256)
void pv_splitk_kernel(const unsigned short* __restrict__ g,
                      const unsigned short* __restrict__ P,
                      const float* __restrict__ stats,
                      float* __restrict__ omidF)
{
    constexpr int TK = 32, LD = TK + 8;
    const long sF = (long)MID * NB, sP = (long)NB * NB;
    const int zb = blockIdx.z / 3, zs = blockIdx.z % 3;
    const unsigned short* Ab = g + (long)zb * sF;
    const unsigned short* Bu = P + (long)zb * sP;
    float* Of = omidF + (long)zb * sF;

    __shared__ unsigned short As[64 * LD];
    __shared__ unsigned short Bs[64 * LD];

    const int tid = threadIdx.x, lane = tid & 63, wave = tid >> 6;
    const int wm = wave >> 1, wn = wave & 1;
    const int m0 = blockIdx.y * 64, n0 = blockIdx.x * 64;
    const int ar = tid >> 2, ac = (tid & 3) * 8;
    const int tk = tid >> 3, tq = (tid & 7) * 8;
    const int lm = lane & 15, kq = (lane >> 4) * 8;

    f32x4 acc[2][2] = {};
    const int kBeg = zs * 768, kEnd = kBeg + 768;
    for (int k0 = kBeg; k0 < kEnd; k0 += TK) {
        {   // A: g [128][2304] bf16 row-major (verbatim !AT path, Kdim=NB)
            short8 v = *(const short8*)(Ab + (long)(m0 + ar) * NB + (k0 + ac));
            *(short8*)(&As[ar * LD + ac]) = v;
        }
        {   // B: P bf16, EXPB staging (verbatim)
            short8 v = *(const short8*)(Bu + (long)(k0 + tk) * NB + (n0 + tq));
            const long krow = (long)zb * NB + (k0 + tk);
            const float mrow = stats[2 * krow];
            const float rinv = stats[2 * krow + 1];
            #pragma unroll
            for (int i = 0; i < 8; i++)
                Bs[(tq + i) * LD + tk] =
                    f2bf(__expf(bf2f((unsigned short)v[i]) - mrow) * rinv);
        }
        __syncthreads();

        bf16x8 afr[2], bfr[2];
        afr[0] = ldfrag(&As[(wm * 32 + lm) * LD + kq]);
        afr[1] = ldfrag(&As[(wm * 32 + 16 + lm) * LD + kq]);
        bfr[0] = ldfrag(&Bs[(wn * 32 + lm) * LD + kq]);
        bfr[1] = ldfrag(&Bs[(wn * 32 + 16 + lm) * LD + kq]);
        #pragma unroll
        for (int i = 0; i < 2; i++)
            #pragma unroll
            for (int j = 0; j < 2; j++)
                acc[i][j] = __builtin_amdgcn_mfma_f32_16x16x32_bf16(afr[i], bfr[j], acc[i][j], 0, 0, 0);
        __syncthreads();
    }

    const int col = lane & 15, rb = (lane >> 4) * 4;
    #pragma unroll
    for (int i = 0; i < 2; i++)
        #pragma unroll
        for (int j = 0; j < 2; j++) {
            const int mB = m0 + wm * 32 + i * 16 + rb;
            const int on = n0 + wn * 32 + j * 16 + col;
            #pragma unroll
            for (int r = 0; r < 4; r++)
                atomicAdd(&Of[(long)(mB + r) * NB + on], acc[i][j][r]);
        }
}

// ---------------------------------------------------------------------------
// zerof: grid-stride fp32 zero.
__global__ __launch_bounds__(256)
void zerof_kernel(float* __restrict__ p, int n)
{
    int stride = gridDim.x * 256;
    for (int i = blockIdx.x * 256 + threadIdx.x; i < n; i += stride) p[i] = 0.0f;
}

// ---------------------------------------------------------------------------
// Row stats over P (R4 verbatim): stats[row] = {max, 1/sum}.
__global__ __launch_bounds__(256)
void softmax_stats(const unsigned short* __restrict__ P, float* __restrict__ stats)
{
    const int row  = blockIdx.x * 4 + (threadIdx.x >> 6);
    const int lane = threadIdx.x & 63;
    const unsigned short* p = P + (long)row * NB;

    float vals[36];
    #pragma unroll
    for (int c = 0; c < 4; c++) {
        short8 v = *(const short8*)(p + c * 512 + lane * 8);
        #pragma unroll
        for (int e = 0; e < 8; e++) vals[c * 8 + e] = bf2f((unsigned short)v[e]);
    }
    {
        short4_t v = *(const short4_t*)(p + 2048 + lane * 4);
        #pragma unroll
        for (int e = 0; e < 4; e++) vals[32 + e] = bf2f((unsigned short)v[e]);
    }

    float mx = vals[0];
    #pragma unroll
    for (int i = 1; i < 36; i++) mx = fmaxf(mx, vals[i]);
    #pragma unroll
    for (int off = 32; off > 0; off >>= 1) mx = fmaxf(mx, __shfl_xor(mx, off, 64));

    float s = 0.f;
    #pragma unroll
    for (int i = 0; i < 36; i++) s += __expf(vals[i] - mx);
    #pragma unroll
    for (int off = 32; off > 0; off >>= 1) s += __shfl_xor(s, off, 64);

    if (lane == 0) {
        stats[2 * (long)row]     = mx;
        stats[2 * (long)row + 1] = 1.0f / s;
    }
}

// ---------------------------------------------------------------------------
// In-place row softmax (fallback path only, R4 verbatim).
__global__ __launch_bounds__(256)
void softmax_rows(unsigned short* __restrict__ P)
{
    const int row  = blockIdx.x * 4 + (threadIdx.x >> 6);
    const int lane = threadIdx.x & 63;
    unsigned short* p = P + (long)row * NB;

    float vals[36];
    #pragma unroll
    for (int c = 0; c < 4; c++) {
        short8 v = *(const short8*)(p + c * 512 + lane * 8);
        #pragma unroll
        for (int e = 0; e < 8; e++) vals[c * 8 + e] = bf2f((unsigned short)v[e]);
    }
    {
        short4_t v = *(const short4_t*)(p + 2048 + lane * 4);
        #pragma unroll
        for (int e = 0; e < 4; e++) vals[32 + e] = bf2f((unsigned short)v[e]);
    }

    float mx = vals[0];
    #pragma unroll
    for (int i = 1; i < 36; i++) mx = fmaxf(mx, vals[i]);
    #pragma unroll
    for (int off = 32; off > 0; off >>= 1) mx = fmaxf(mx, __shfl_xor(mx, off, 64));

    float s = 0.f;
    #pragma unroll
    for (int i = 0; i < 36; i++) { vals[i] = __expf(vals[i] - mx); s += vals[i]; }
    #pragma unroll
    for (int off = 32; off > 0; off >>= 1) s += __shfl_xor(s, off, 64);
    const float rs = 1.0f / s;

    #pragma unroll
    for (int c = 0; c < 4; c++) {
        short8 w;
        #pragma unroll
        for (int e = 0; e < 8; e++) w[e] = (short)f2bf(vals[c * 8 + e] * rs);
        *(short8*)(p + c * 512 + lane * 8) = w;
    }
    {
        short4_t w;
        #pragma unroll
        for (int e = 0; e < 4; e++) w[e] = (short)f2bf(vals[32 + e] * rs);
        *(short4_t*)(p + 2048 + lane * 4) = w;
    }
}

// ---------------------------------------------------------------------------
extern "C" void kernel_launch(void* const* d_in, const int* in_sizes, int n_in,
                              void* d_out, int out_size, void* d_ws, size_t ws_size,
                              hipStream_t stream)
{
    const float* x    = (const float*)d_in[0];
    const float* x_h  = (const float*)d_in[1];
    const float* x_v  = (const float*)d_in[2];
    const float* Wa   = (const float*)d_in[3];
    const float* ba   = (const float*)d_in[4];
    const float* ga   = (const float*)d_in[5];
    const float* ta   = (const float*)d_in[6];
    const float* Wv   = (const float*)d_in[7];
    const float* bv   = (const float*)d_in[8];
    const float* gv   = (const float*)d_in[9];
    const float* tv   = (const float*)d_in[10];
    const float* Wgav = (const float*)d_in[11];
    const float* bgav = (const float*)d_in[12];
    const float* Wgah = (const float*)d_in[13];
    const float* bgah = (const float*)d_in[14];
    const float* Wfav = (const float*)d_in[15];
    const float* bfav = (const float*)d_in[16];
    const float* Wfah = (const float*)d_in[17];
    const float* bfah = (const float*)d_in[18];
    float* out = (float*)d_out;

    const long sX = (long)CC * NB;        // 1179648
    const long sF = (long)MID * NB;       // 294912
    const long sP = (long)NB * NB;        // 5308416
    const long HALF = (long)BB * sX;      // o_h at out[0], o_v at out[HALF]

    const dim3 blk(256);
    unsigned short* ws = (unsigned short*)d_ws;

    // ---- big-path ws layout (shorts), total 54,733,824 shorts = 109,467,648 B
    //  0        WaE..WfahE  (6 x 65536)
    //  393216   biases f32 (1536)                    -> 396288
    //  396288   stats  f32 (2*8*2304 = 36864 f)      -> 470016
    //  470016   fa   (2359296)                       -> 2829312
    //  2829312  gav                                  -> 5188608
    //  5188608  gah                                  -> 7547904
    //  7547904  SCRATCH: fv/fh (2359296) then omidF f32 (2359296 f = 4718592 sh)
    //                                                -> 12266496
    //  12266496 P (8*5308416)                        -> 54733824
    constexpr size_t WS_BIG = 109467648ull;

    if (ws_size >= WS_BIG) {
        unsigned short* WaE   = ws;
        unsigned short* WvE   = ws + 65536;
        unsigned short* WgavE = ws + 131072;
        unsigned short* WgahE = ws + 196608;
        unsigned short* WfavE = ws + 262144;
        unsigned short* WfahE = ws + 327680;
        float* biases = (float*)(ws + 393216);
        float* stats  = (float*)(ws + 396288);
        unsigned short* fa   = ws + 470016;
        unsigned short* gav  = ws + 2829312;
        unsigned short* gah  = ws + 5188608;
        unsigned short* fq   = ws + 7547904;        // fv, later fh
        float* omidF         = (float*)(ws + 7547904);  // overlays fq when dead
        unsigned short* P    = ws + 12266496;

        float* baE   = biases;
        float* bvE   = biases + 128;
        float* bgavF = biases + 256;
        float* bgahF = biases + 384;
        float* bfavF = biases + 512;
        float* bfahF = biases + 1024;

        fold_kernel<<<256, 256, 0, stream>>>(Wa, ba, ga, ta, Wv, bv, gv, tv,
                                             Wgav, bgav, Wgah, bgah, Wfav, bfav, Wfah, bfah,
                                             WaE, WvE, WgavE, WgahE, WfavE, WfahE, biases);

        // proj4: cls 0=fa(relu) 1=fv(relu) 2=gav 3=gah  (reluMask 0b0011)
        proj4_kernel<<<dim3(36, 2, 32), blk, 0, stream>>>(
            WaE, WvE, WgavE, WgahE,
            baE, bvE, bgavF, bgahF,
            x, x_v, x, x,
            fa, fq, gav, gah, 3);

        // ---- direction v -> o_v at out+HALF ----
        gemm_kernel<true,0,false,false,false><<<dim3(36,36,8), blk, 0, stream>>>(
            fq, sF, fa, sF, P, sP, nullptr, nullptr, 0, nullptr, NB, MID, NB, ATT_SCALE);
        softmax_stats<<<BB * NB / 4, blk, 0, stream>>>(P, stats);
        zerof_kernel<<<1024, blk, 0, stream>>>(omidF, (int)(BB * sF));   // fv dead now
        pv_splitk_kernel<<<dim3(36, 2, 24), blk, 0, stream>>>(gav, P, stats, omidF);
        gemm_kernel<false,3,true,true,false><<<dim3(36,8,8), blk, 0, stream>>>(
            WfavE, 0, omidF, sF, out + HALF, sX, bfavF, x, sX, nullptr, CC, MID, NB, 1.f);

        // deferred fh projection into SCRATCH (omidF dead after final_v)
        proj4_kernel<<<dim3(36, 2, 8), blk, 0, stream>>>(
            WvE, WvE, WvE, WvE,
            bvE, bvE, bvE, bvE,
            x_h, x_h, x_h, x_h,
            fq, fq, fq, fq, 1);

        // ---- direction h -> o_h at out[0] ----
        gemm_kernel<true,0,false,false,false><<<dim3(36,36,8), blk, 0, stream>>>(
            fq, sF, fa, sF, P, sP, nullptr, nullptr, 0, nullptr, NB, MID, NB, ATT_SCALE);
        softmax_stats<<<BB * NB / 4, blk, 0, stream>>>(P, stats);
        zerof_kernel<<<1024, blk, 0, stream>>>(omidF, (int)(BB * sF));   // fh dead now
        pv_splitk_kernel<<<dim3(36, 2, 24), blk, 0, stream>>>(gah, P, stats, omidF);
        gemm_kernel<false,3,true,true,false><<<dim3(36,8,8), blk, 0, stream>>>(
            WfahE, 0, omidF, sF, out, sX, bfahF, x, sX, nullptr, CC, MID, NB, 1.f);

        return;
    }

    // ---------------- fallback: exact Round-3 per-batch path ----------------
    constexpr size_t WS_NEED = 7280640;
    if (ws_size < WS_NEED) return;

    unsigned short* WaE   = ws;
    unsigned short* WvE   = ws + 65536;
    unsigned short* WgavE = ws + 131072;
    unsigned short* WgahE = ws + 196608;
    unsigned short* WfavE = ws + 262144;
    unsigned short* WfahE = ws + 327680;
    float* biases = (float*)(ws + 393216);
    unsigned short* fab  = ws + 396288;
    unsigned short* qb   = ws + 691200;
    unsigned short* gb   = ws + 986112;
    unsigned short* omid = ws + 1281024;
    unsigned short* Pb = (unsigned short*)d_out;

    float* baE   = biases;
    float* bvE   = biases + 128;
    float* bgavF = biases + 256;
    float* bgahF = biases + 384;
    float* bfavF = biases + 512;
    float* bfahF = biases + 1024;

    fold_kernel<<<256, 256, 0, stream>>>(Wa, ba, ga, ta, Wv, bv, gv, tv,
                                         Wgav, bgav, Wgah, bgah, Wfav, bfav, Wfah, bfah,
                                         WaE, WvE, WgavE, WgahE, WfavE, WfahE, biases);

    for (int b = 0; b < BB; b++) {
        const float* xb  = x   + (long)b * sX;
        const float* xqb = x_v + (long)b * sX;
        gemm_kernel<false,1,true,false,false><<<dim3(36,2,1), blk, 0, stream>>>(WaE,   0, xb,  0, fab, 0, baE,   nullptr, 0, nullptr, MID, CC, NB, 1.f);
        gemm_kernel<false,1,true,false,false><<<dim3(36,2,1), blk, 0, stream>>>(WvE,   0, xqb, 0, qb,  0, bvE,   nullptr, 0, nullptr, MID, CC, NB, 1.f);
        gemm_kernel<false,2,true,false,false><<<dim3(36,2,1), blk, 0, stream>>>(WgavE, 0, xb,  0, gb,  0, bgavF, nullptr, 0, nullptr, MID, CC, NB, 1.f);
        gemm_kernel<true,0,false,false,false><<<dim3(36,36,1), blk, 0, stream>>>(qb, 0, fab, 0, Pb, 0, nullptr, nullptr, 0, nullptr, NB, MID, NB, ATT_SCALE);
        softmax_rows<<<NB / 4, blk, 0, stream>>>(Pb);
        gemm_kernel<false,0,false,false,false><<<dim3(36,2,1), blk, 0, stream>>>(gb, 0, Pb, 0, omid + (long)b * sF, 0, nullptr, nullptr, 0, nullptr, MID, NB, NB, 1.f);
    }
    gemm_kernel<false,3,false,true,false><<<dim3(36,8,8), blk, 0, stream>>>(WfavE, 0, omid, sF, out + HALF, sX, bfavF, x, sX, nullptr, CC, MID, NB, 1.f);

    for (int b = 0; b < BB; b++) {
        const float* xb  = x   + (long)b * sX;
        const float* xqb = x_h + (long)b * sX;
        gemm_kernel<false,1,true,false,false><<<dim3(36,2,1), blk, 0, stream>>>(WaE,   0, xb,  0, fab, 0, baE,   nullptr, 0, nullptr, MID, CC, NB, 1.f);
        gemm_kernel<false,1,true,false,false><<<dim3(36,2,1), blk, 0, stream>>>(WvE,   0, xqb, 0, qb,  0, bvE,   nullptr, 0, nullptr, MID, CC, NB, 1.f);
        gemm_kernel<false,2,true,false,false><<<dim3(36,2,1), blk, 0, stream>>>(WgahE, 0, xb,  0, gb,  0, bgahF, nullptr, 0, nullptr, MID, CC, NB, 1.f);
        gemm_kernel<true,0,false,false,false><<<dim3(36,36,1), blk, 0, stream>>>(qb, 0, fab, 0, Pb, 0, nullptr, nullptr, 0, nullptr, NB, MID, NB, ATT_SCALE);
        softmax_rows<<<NB / 4, blk, 0, stream>>>(Pb);
        gemm_kernel<false,0,false,false,false><<<dim3(36,2,1), blk, 0, stream>>>(gb, 0, Pb, 0, omid + (long)b * sF, 0, nullptr, nullptr, 0, nullptr, MID, NB, NB, 1.f);
    }
    gemm_kernel<false,3,false,true,false><<<dim3(36,8,8), blk, 0, stream>>>(WfahE, 0, omid, sF, out, sX, bfahF, x, sX, nullptr, CC, MID, NB, 1.f);

    (void)in_sizes; (void)n_in; (void)out_size;
}

// Round 4
// 476.811 us; speedup vs baseline: 1.4161x; 1.2793x over previous
//
#include <hip/hip_runtime.h>

// MirrorAttention on MI355X (gfx950). Round 8: kill the LDS transpose-staging
// bank conflicts (3.98e7/dispatch, 8-way on every ds_write_b16) in the hot
// loops:
//   - transpose_kernel: fa/fq [128][NB] -> [NB][128] (tiny, 28MB traffic).
//   - scoreT: P^T = mfma(faT, fqT), both operands row-major vectorized staging
//     (verified !AT pattern); epilogue writes P^T bf16 AND accumulates
//     per-query exp-sums (max-free softmax: S bounded; sums taken over the
//     same bf16 values PV reads -> exactly consistent normalization).
//     softmax_stats dispatches + 85MB P re-read eliminated.
//   - pv2: B = P^T staged row-major vectorized with exp*rinv fused in regs;
//     A/g staging, MFMA, split-K=3 fp32-atomicAdd epilogue verbatim R7.
//   - proj4 / final / fold / fallback: verbatim R7 (610us PASS).

typedef __attribute__((ext_vector_type(8))) short short8;
typedef __attribute__((ext_vector_type(4))) short short4_t;
typedef __attribute__((ext_vector_type(8))) __bf16 bf16x8;
typedef __attribute__((ext_vector_type(4))) float f32x4;

#define DEV __device__ __forceinline__

constexpr int BB = 8, CC = 512, MID = 128, NB = 2304;
constexpr float ATT_SCALE = 0.08838834764831845f;   // 128^-0.5
constexpr float RSQ = 0.9999950000374998f;          // 1/sqrt(1+1e-5)

DEV float bf2f(unsigned short u) {
    unsigned int x = ((unsigned int)u) << 16;
    return __builtin_bit_cast(float, x);
}
DEV unsigned short f2bf(float f) {   // round-to-nearest-even
    unsigned int x = __builtin_bit_cast(unsigned int, f);
    x += 0x7fffu + ((x >> 16) & 1u);
    return (unsigned short)(x >> 16);
}
DEV bf16x8 ldfrag(const unsigned short* p) {
    return __builtin_bit_cast(bf16x8, *(const short8*)p);
}

// ---------------------------------------------------------------------------
// fold kernel (R7 verbatim)
__global__ __launch_bounds__(256)
void fold_kernel(const float* __restrict__ Wa, const float* __restrict__ ba,
                 const float* __restrict__ ga, const float* __restrict__ ta,
                 const float* __restrict__ Wv, const float* __restrict__ bv,
                 const float* __restrict__ gv, const float* __restrict__ tv,
                 const float* __restrict__ Wgav, const float* __restrict__ bgav,
                 const float* __restrict__ Wgah, const float* __restrict__ bgah,
                 const float* __restrict__ Wfav, const float* __restrict__ bfav,
                 const float* __restrict__ Wfah, const float* __restrict__ bfah,
                 unsigned short* __restrict__ WaE, unsigned short* __restrict__ WvE,
                 unsigned short* __restrict__ WgavE, unsigned short* __restrict__ WgahE,
                 unsigned short* __restrict__ WfavE, unsigned short* __restrict__ WfahE,
                 float* __restrict__ biases)
{
    int idx = blockIdx.x * 256 + threadIdx.x;
    if (idx < 65536) {
        int m = idx >> 9;                  // row of [128][512]
        WaE[idx]   = f2bf(ga[m] * RSQ * Wa[idx]);
        WvE[idx]   = f2bf(gv[m] * RSQ * Wv[idx]);
        WgavE[idx] = f2bf(Wgav[idx]);
        WgahE[idx] = f2bf(Wgah[idx]);
        WfavE[idx] = f2bf(Wfav[idx]);      // [512][128] flat
        WfahE[idx] = f2bf(Wfah[idx]);
    }
    if (idx < 128) {
        biases[idx]       = ba[idx] * ga[idx] * RSQ + ta[idx];
        biases[128 + idx] = bv[idx] * gv[idx] * RSQ + tv[idx];
        biases[256 + idx] = bgav[idx];
        biases[384 + idx] = bgah[idx];
    }
    if (idx < 512) {
        biases[512 + idx]  = bfav[idx];
        biases[1024 + idx] = bfah[idx];
    }
}

// ---------------------------------------------------------------------------
// Generic MFMA GEMM (R7 verbatim; big path uses it only for final5; fallback
// uses all variants).
template<bool AT, int EPI, bool BF32, bool OF32, bool EXPB>
__global__ __launch_bounds__(256)
void gemm_kernel(const unsigned short* __restrict__ A, long sAb,
                 const void* __restrict__ Bm, long sBb,
                 void* __restrict__ Out, long sOb,
                 const float* __restrict__ bias,
                 const float* __restrict__ resid, long sRb,
                 const float* __restrict__ stats,
                 int Mdim, int Kdim, int Ndim, float outscale)
{
    constexpr int TM = 64, TN = 64, TK = 32, LD = TK + 8;
    __shared__ unsigned short As[TM * LD];
    __shared__ unsigned short Bs[TN * LD];

    const int tid  = threadIdx.x;
    const int lane = tid & 63;
    const int wave = tid >> 6;
    const int wm = wave >> 1, wn = wave & 1;
    const int m0 = blockIdx.y * TM, n0 = blockIdx.x * TN;
    const int z  = blockIdx.z;

    const unsigned short* Ab = A + (long)z * sAb;

    f32x4 acc[2][2] = {};

    const int ar = tid >> 2, ac = (tid & 3) * 8;   // row-major A staging
    const int tk = tid >> 3, tq = (tid & 7) * 8;   // K-major (transpose) staging
    const int lm = lane & 15, kq = (lane >> 4) * 8;

    for (int k0 = 0; k0 < Kdim; k0 += TK) {
        if constexpr (!AT) {
            short8 v = *(const short8*)(Ab + (long)(m0 + ar) * Kdim + (k0 + ac));
            *(short8*)(&As[ar * LD + ac]) = v;
        } else {
            short8 v = *(const short8*)(Ab + (long)(k0 + tk) * Mdim + (m0 + tq));
            #pragma unroll
            for (int i = 0; i < 8; i++) As[(tq + i) * LD + tk] = (unsigned short)v[i];
        }
        if constexpr (BF32) {
            const float* Bf = (const float*)Bm + (long)z * sBb;
            f32x4 a0 = *(const f32x4*)(Bf + (long)(k0 + tk) * Ndim + (n0 + tq));
            f32x4 a1 = *(const f32x4*)(Bf + (long)(k0 + tk) * Ndim + (n0 + tq) + 4);
            #pragma unroll
            for (int i = 0; i < 4; i++) Bs[(tq + i) * LD + tk]     = f2bf(a0[i]);
            #pragma unroll
            for (int i = 0; i < 4; i++) Bs[(tq + 4 + i) * LD + tk] = f2bf(a1[i]);
        } else {
            const unsigned short* Bu = (const unsigned short*)Bm + (long)z * sBb;
            short8 v = *(const short8*)(Bu + (long)(k0 + tk) * Ndim + (n0 + tq));
            if constexpr (EXPB) {
                const long krow = (long)z * NB + (k0 + tk);
                const float mrow = stats[2 * krow];
                const float rinv = stats[2 * krow + 1];
                #pragma unroll
                for (int i = 0; i < 8; i++)
                    Bs[(tq + i) * LD + tk] =
                        f2bf(__expf(bf2f((unsigned short)v[i]) - mrow) * rinv);
            } else {
                #pragma unroll
                for (int i = 0; i < 8; i++) Bs[(tq + i) * LD + tk] = (unsigned short)v[i];
            }
        }
        __syncthreads();

        bf16x8 afr[2], bfr[2];
        afr[0] = __builtin_bit_cast(bf16x8, *(const short8*)(&As[(wm * 32 + lm) * LD + kq]));
        afr[1] = __builtin_bit_cast(bf16x8, *(const short8*)(&As[(wm * 32 + 16 + lm) * LD + kq]));
        bfr[0] = __builtin_bit_cast(bf16x8, *(const short8*)(&Bs[(wn * 32 + lm) * LD + kq]));
        bfr[1] = __builtin_bit_cast(bf16x8, *(const short8*)(&Bs[(wn * 32 + 16 + lm) * LD + kq]));
        #pragma unroll
        for (int i = 0; i < 2; i++)
            #pragma unroll
            for (int j = 0; j < 2; j++)
                acc[i][j] = __builtin_amdgcn_mfma_f32_16x16x32_bf16(afr[i], bfr[j], acc[i][j], 0, 0, 0);
        __syncthreads();
    }

    const float* Rb = nullptr;
    if constexpr (EPI == 3) Rb = resid + (long)z * sRb;

    const int col = lane & 15, rb = (lane >> 4) * 4;
    #pragma unroll
    for (int i = 0; i < 2; i++) {
        #pragma unroll
        for (int j = 0; j < 2; j++) {
            const int mB = m0 + wm * 32 + i * 16 + rb;
            const int on = n0 + wn * 32 + j * 16 + col;
            #pragma unroll
            for (int r = 0; r < 4; r++) {
                const int m = mB + r;
                float v = acc[i][j][r];
                if constexpr (EPI == 0) {
                    v *= outscale;
                } else {
                    v += bias[m];
                    if constexpr (EPI == 1) v = fmaxf(v, 0.0f);
                    if constexpr (EPI == 3) v += Rb[(long)m * Ndim + on];
                }
                if constexpr (OF32) {
                    float* Of = (float*)Out + (long)z * sOb;
                    Of[(long)m * Ndim + on] = v;
                } else {
                    unsigned short* Ou = (unsigned short*)Out + (long)z * sOb;
                    Ou[(long)m * Ndim + on] = f2bf(v);
                }
            }
        }
    }
}

// ---------------------------------------------------------------------------
// proj4 (R7 verbatim): four 1x1 projections fused.
__global__ __launch_bounds__(256)
void proj4_kernel(const unsigned short* __restrict__ W0, const unsigned short* __restrict__ W1,
                  const unsigned short* __restrict__ W2, const unsigned short* __restrict__ W3,
                  const float* __restrict__ b0, const float* __restrict__ b1,
                  const float* __restrict__ b2, const float* __restrict__ b3,
                  const float* __restrict__ S0, const float* __restrict__ S1,
                  const float* __restrict__ S2, const float* __restrict__ S3,
                  unsigned short* __restrict__ D0, unsigned short* __restrict__ D1,
                  unsigned short* __restrict__ D2, unsigned short* __restrict__ D3,
                  int reluMask)
{
    constexpr int TK = 32, LD = TK + 8;
    const long sF = (long)MID * NB, sX = (long)CC * NB;
    const int zz = blockIdx.z, cls = zz >> 3, b = zz & 7;
    const unsigned short* W = cls == 0 ? W0 : cls == 1 ? W1 : cls == 2 ? W2 : W3;
    const float* bi = cls == 0 ? b0 : cls == 1 ? b1 : cls == 2 ? b2 : b3;
    const float* Bf = (cls == 0 ? S0 : cls == 1 ? S1 : cls == 2 ? S2 : S3) + (long)b * sX;
    unsigned short* outp = (cls == 0 ? D0 : cls == 1 ? D1 : cls == 2 ? D2 : D3) + (long)b * sF;
    const bool relu = (reluMask >> cls) & 1;

    __shared__ unsigned short As[64 * LD];
    __shared__ unsigned short Bs[64 * LD];

    const int tid = threadIdx.x, lane = tid & 63, wave = tid >> 6;
    const int wm = wave >> 1, wn = wave & 1;
    const int m0 = blockIdx.y * 64, n0 = blockIdx.x * 64;
    const int ar = tid >> 2, ac = (tid & 3) * 8;
    const int tk = tid >> 3, tq = (tid & 7) * 8;
    const int lm = lane & 15, kq = (lane >> 4) * 8;

    f32x4 acc[2][2] = {};
    for (int k0 = 0; k0 < CC; k0 += TK) {
        short8 v = *(const short8*)(W + (long)(m0 + ar) * CC + (k0 + ac));
        *(short8*)(&As[ar * LD + ac]) = v;
        f32x4 a0 = *(const f32x4*)(Bf + (long)(k0 + tk) * NB + (n0 + tq));
        f32x4 a1 = *(const f32x4*)(Bf + (long)(k0 + tk) * NB + (n0 + tq) + 4);
        #pragma unroll
        for (int i = 0; i < 4; i++) Bs[(tq + i) * LD + tk]     = f2bf(a0[i]);
        #pragma unroll
        for (int i = 0; i < 4; i++) Bs[(tq + 4 + i) * LD + tk] = f2bf(a1[i]);
        __syncthreads();
        bf16x8 afr[2], bfr[2];
        afr[0] = ldfrag(&As[(wm * 32 + lm) * LD + kq]);
        afr[1] = ldfrag(&As[(wm * 32 + 16 + lm) * LD + kq]);
        bfr[0] = ldfrag(&Bs[(wn * 32 + lm) * LD + kq]);
        bfr[1] = ldfrag(&Bs[(wn * 32 + 16 + lm) * LD + kq]);
        #pragma unroll
        for (int i = 0; i < 2; i++)
            #pragma unroll
            for (int j = 0; j < 2; j++)
                acc[i][j] = __builtin_amdgcn_mfma_f32_16x16x32_bf16(afr[i], bfr[j], acc[i][j], 0, 0, 0);
        __syncthreads();
    }

    const int col = lane & 15, rb = (lane >> 4) * 4;
    #pragma unroll
    for (int i = 0; i < 2; i++) {
        #pragma unroll
        for (int j = 0; j < 2; j++) {
            const int mB = m0 + wm * 32 + i * 16 + rb;
            const int on = n0 + wn * 32 + j * 16 + col;
            #pragma unroll
            for (int r = 0; r < 4; r++) {
                const int m = mB + r;
                float v = acc[i][j][r] + bi[m];
                if (relu) v = fmaxf(v, 0.0f);
                outp[(long)m * NB + on] = f2bf(v);
            }
        }
    }
}

// ---------------------------------------------------------------------------
// transpose_kernel: src [128][NB] bf16 -> dst [NB][128]. grid (36, 2, 8).
// Staging uses the verified else-path transpose idiom; output rows vectorized.
__global__ __launch_bounds__(256)
void transpose_kernel(const unsigned short* __restrict__ src,
                      unsigned short* __restrict__ dst)
{
    constexpr int LT = 72;
    const long sF = (long)MID * NB;
    const int b = blockIdx.z;
    const unsigned short* s = src + (long)b * sF;
    unsigned short* d = dst + (long)b * sF;
    const int n0 = blockIdx.x * 64, m0 = blockIdx.y * 64;
    const int tid = threadIdx.x;
    const int tk = tid >> 3, tq = (tid & 7) * 8;   // tk 0..31, tq 0..56

    __shared__ unsigned short T[64 * LT];          // T[n][m]

    #pragma unroll
    for (int mm = 0; mm < 64; mm += 32) {
        short8 v = *(const short8*)(s + (long)(m0 + mm + tk) * NB + n0 + tq);
        #pragma unroll
        for (int e = 0; e < 8; e++) T[(tq + e) * LT + mm + tk] = (unsigned short)v[e];
    }
    __syncthreads();
    #pragma unroll
    for (int rr = 0; rr < 2; rr++) {
        int c = rr * 256 + tid;
        int nr = c >> 3, mc = (c & 7) * 8;
        *(short8*)(d + (long)(n0 + nr) * MID + m0 + mc) = *(const short8*)(&T[nr * LT + mc]);
    }
}

// ---------------------------------------------------------------------------
// scoreT: PT[key m][query n] = bf16(scale * sum_c faT[m][c]*fqT[n][c]); fused
// per-query exp-sums (max-free) -> atomicAdd(sums[z*NB + n]).
// Both operands staged row-major vectorized (verified !AT pattern, Kdim=128).
// grid (36 query-tiles, 36 key-tiles, 8 z).
__global__ __launch_bounds__(256)
void scoreT_kernel(const unsigned short* __restrict__ faT,
                   const unsigned short* __restrict__ fqT,
                   unsigned short* __restrict__ PT,
                   float* __restrict__ sums)
{
    constexpr int LD = 40;
    const long sF = (long)MID * NB, sP = (long)NB * NB;
    const int z = blockIdx.z;
    const unsigned short* Ab = faT + (long)z * sF;   // [NB keys][128]
    const unsigned short* Bb = fqT + (long)z * sF;   // [NB queries][128]
    unsigned short* Ou = PT + (long)z * sP;
    float* sm = sums + (long)z * NB;

    __shared__ unsigned short As[64 * LD];
    __shared__ unsigned short Bs[64 * LD];

    const int tid = threadIdx.x, lane = tid & 63, wave = tid >> 6;
    const int wm = wave >> 1, wn = wave & 1;
    const int m0 = blockIdx.y * 64, n0 = blockIdx.x * 64;
    const int ar = tid >> 2, ac = (tid & 3) * 8;
    const int lm = lane & 15, kq = (lane >> 4) * 8;

    f32x4 acc[2][2] = {};
    #pragma unroll
    for (int k0 = 0; k0 < MID; k0 += 32) {
        *(short8*)(&As[ar * LD + ac]) = *(const short8*)(Ab + (long)(m0 + ar) * MID + (k0 + ac));
        *(short8*)(&Bs[ar * LD + ac]) = *(const short8*)(Bb + (long)(n0 + ar) * MID + (k0 + ac));
        __syncthreads();
        bf16x8 afr[2], bfr[2];
        afr[0] = ldfrag(&As[(wm * 32 + lm) * LD + kq]);
        afr[1] = ldfrag(&As[(wm * 32 + 16 + lm) * LD + kq]);
        bfr[0] = ldfrag(&Bs[(wn * 32 + lm) * LD + kq]);
        bfr[1] = ldfrag(&Bs[(wn * 32 + 16 + lm) * LD + kq]);
        #pragma unroll
        for (int i = 0; i < 2; i++)
            #pragma unroll
            for (int j = 0; j < 2; j++)
                acc[i][j] = __builtin_amdgcn_mfma_f32_16x16x32_bf16(afr[i], bfr[j], acc[i][j], 0, 0, 0);
        __syncthreads();
    }

    // epilogue: acc[i][j][r] -> (key row mB+r, query col on). Write PT and
    // accumulate column sums of exp(bf16 value) (softmax over keys = rows).
    const int col = lane & 15, rb = (lane >> 4) * 4;
    float csum[2] = {0.f, 0.f};
    #pragma unroll
    for (int i = 0; i < 2; i++) {
        #pragma unroll
        for (int j = 0; j < 2; j++) {
            const int mB = m0 + wm * 32 + i * 16 + rb;
            const int on = n0 + wn * 32 + j * 16 + col;
            #pragma unroll
            for (int r = 0; r < 4; r++) {
                unsigned short u = f2bf(acc[i][j][r] * ATT_SCALE);
                Ou[(long)(mB + r) * NB + on] = u;
                csum[j] += __expf(bf2f(u));
            }
        }
    }
    // sum over the 4 (lane>>4) row-groups: lanes with equal (lane&15)
    csum[0] += __shfl_xor(csum[0], 16, 64);
    csum[0] += __shfl_xor(csum[0], 32, 64);
    csum[1] += __shfl_xor(csum[1], 16, 64);
    csum[1] += __shfl_xor(csum[1], 32, 64);
    if (lane < 16) {
        atomicAdd(&sm[n0 + wn * 32 + lane],      csum[0]);
        atomicAdd(&sm[n0 + wn * 32 + 16 + lane], csum[1]);
    }
}

// ---------------------------------------------------------------------------
// stats_inv: p = 1/p over BB*NB floats.
__global__ __launch_bounds__(256)
void stats_inv_kernel(float* __restrict__ p)
{
    int idx = blockIdx.x * 256 + threadIdx.x;
    if (idx < BB * NB) p[idx] = 1.0f / p[idx];
}

// ---------------------------------------------------------------------------
// pv2: omidF[m,j] += sum_{k in slice} g[m,k]*exp(PT[j,k])*rinv[k]. B staged
// row-major vectorized from PT with exp*rinv fused in registers. A staging,
// MFMA, split-K=3 fp32 atomicAdd epilogue verbatim R7. grid (36, 2, 24).
__global__ __launch_bounds__(256)
void pv2_kernel(const unsigned short* __restrict__ g,
                const unsigned short* __restrict__ PT,
                const float* __restrict__ rinv,
                float* __restrict__ omidF)
{
    constexpr int TK = 32, LD = TK + 8;
    const long sF = (long)MID * NB, sP = (long)NB * NB;
    const int zb = blockIdx.z / 3, zs = blockIdx.z % 3;
    const unsigned short* Ab = g + (long)zb * sF;    // [128][NB]
    const unsigned short* Bt = PT + (long)zb * sP;   // [key j][query k]
    const float* rv = rinv + (long)zb * NB;
    float* Of = omidF + (long)zb * sF;

    __shared__ unsigned short As[64 * LD];
    __shared__ unsigned short Bs[64 * LD];

    const int tid = threadIdx.x, lane = tid & 63, wave = tid >> 6;
    const int wm = wave >> 1, wn = wave & 1;
    const int m0 = blockIdx.y * 64, n0 = blockIdx.x * 64;
    const int ar = tid >> 2, ac = (tid & 3) * 8;
    const int lm = lane & 15, kq = (lane >> 4) * 8;

    f32x4 acc[2][2] = {};
    const int kBeg = zs * 768, kEnd = kBeg + 768;
    for (int k0 = kBeg; k0 < kEnd; k0 += TK) {
        *(short8*)(&As[ar * LD + ac]) = *(const short8*)(Ab + (long)(m0 + ar) * NB + (k0 + ac));
        {
            short8 v = *(const short8*)(Bt + (long)(n0 + ar) * NB + (k0 + ac));
            f32x4 r0 = *(const f32x4*)(rv + k0 + ac);
            f32x4 r1 = *(const f32x4*)(rv + k0 + ac + 4);
            short8 w;
            #pragma unroll
            for (int e = 0; e < 4; e++)
                w[e] = (short)f2bf(__expf(bf2f((unsigned short)v[e])) * r0[e]);
            #pragma unroll
            for (int e = 0; e < 4; e++)
                w[4 + e] = (short)f2bf(__expf(bf2f((unsigned short)v[4 + e])) * r1[e]);
            *(short8*)(&Bs[ar * LD + ac]) = w;
        }
        __syncthreads();

        bf16x8 afr[2], bfr[2];
        afr[0] = ldfrag(&As[(wm * 32 + lm) * LD + kq]);
        afr[1] = ldfrag(&As[(wm * 32 + 16 + lm) * LD + kq]);
        bfr[0] = ldfrag(&Bs[(wn * 32 + lm) * LD + kq]);
        bfr[1] = ldfrag(&Bs[(wn * 32 + 16 + lm) * LD + kq]);
        #pragma unroll
        for (int i = 0; i < 2; i++)
            #pragma unroll
            for (int j = 0; j < 2; j++)
                acc[i][j] = __builtin_amdgcn_mfma_f32_16x16x32_bf16(afr[i], bfr[j], acc[i][j], 0, 0, 0);
        __syncthreads();
    }

    const int col = lane & 15, rb = (lane >> 4) * 4;
    #pragma unroll
    for (int i = 0; i < 2; i++)
        #pragma unroll
        for (int j = 0; j < 2; j++) {
            const int mB = m0 + wm * 32 + i * 16 + rb;
            const int on = n0 + wn * 32 + j * 16 + col;
            #pragma unroll
            for (int r = 0; r < 4; r++)
                atomicAdd(&Of[(long)(mB + r) * NB + on], acc[i][j][r]);
        }
}

// ---------------------------------------------------------------------------
// zerof: grid-stride fp32 zero (R7 verbatim).
__global__ __launch_bounds__(256)
void zerof_kernel(float* __restrict__ p, int n)
{
    int stride = gridDim.x * 256;
    for (int i = blockIdx.x * 256 + threadIdx.x; i < n; i += stride) p[i] = 0.0f;
}

// ---------------------------------------------------------------------------
// In-place row softmax (fallback path only, R3/R7 verbatim).
__global__ __launch_bounds__(256)
void softmax_rows(unsigned short* __restrict__ P)
{
    const int row  = blockIdx.x * 4 + (threadIdx.x >> 6);
    const int lane = threadIdx.x & 63;
    unsigned short* p = P + (long)row * NB;

    float vals[36];
    #pragma unroll
    for (int c = 0; c < 4; c++) {
        short8 v = *(const short8*)(p + c * 512 + lane * 8);
        #pragma unroll
        for (int e = 0; e < 8; e++) vals[c * 8 + e] = bf2f((unsigned short)v[e]);
    }
    {
        short4_t v = *(const short4_t*)(p + 2048 + lane * 4);
        #pragma unroll
        for (int e = 0; e < 4; e++) vals[32 + e] = bf2f((unsigned short)v[e]);
    }

    float mx = vals[0];
    #pragma unroll
    for (int i = 1; i < 36; i++) mx = fmaxf(mx, vals[i]);
    #pragma unroll
    for (int off = 32; off > 0; off >>= 1) mx = fmaxf(mx, __shfl_xor(mx, off, 64));

    float s = 0.f;
    #pragma unroll
    for (int i = 0; i < 36; i++) { vals[i] = __expf(vals[i] - mx); s += vals[i]; }
    #pragma unroll
    for (int off = 32; off > 0; off >>= 1) s += __shfl_xor(s, off, 64);
    const float rs = 1.0f / s;

    #pragma unroll
    for (int c = 0; c < 4; c++) {
        short8 w;
        #pragma unroll
        for (int e = 0; e < 8; e++) w[e] = (short)f2bf(vals[c * 8 + e] * rs);
        *(short8*)(p + c * 512 + lane * 8) = w;
    }
    {
        short4_t w;
        #pragma unroll
        for (int e = 0; e < 4; e++) w[e] = (short)f2bf(vals[32 + e] * rs);
        *(short4_t*)(p + 2048 + lane * 4) = w;
    }
}

// ---------------------------------------------------------------------------
extern "C" void kernel_launch(void* const* d_in, const int* in_sizes, int n_in,
                              void* d_out, int out_size, void* d_ws, size_t ws_size,
                              hipStream_t stream)
{
    const float* x    = (const float*)d_in[0];
    const float* x_h  = (const float*)d_in[1];
    const float* x_v  = (const float*)d_in[2];
    const float* Wa   = (const float*)d_in[3];
    const float* ba   = (const float*)d_in[4];
    const float* ga   = (const float*)d_in[5];
    const float* ta   = (const float*)d_in[6];
    const float* Wv   = (const float*)d_in[7];
    const float* bv   = (const float*)d_in[8];
    const float* gv   = (const float*)d_in[9];
    const float* tv   = (const float*)d_in[10];
    const float* Wgav = (const float*)d_in[11];
    const float* bgav = (const float*)d_in[12];
    const float* Wgah = (const float*)d_in[13];
    const float* bgah = (const float*)d_in[14];
    const float* Wfav = (const float*)d_in[15];
    const float* bfav = (const float*)d_in[16];
    const float* Wfah = (const float*)d_in[17];
    const float* bfah = (const float*)d_in[18];
    float* out = (float*)d_out;

    const long sX = (long)CC * NB;        // 1179648
    const long sF = (long)MID * NB;       // 294912
    const long sP = (long)NB * NB;        // 5308416
    const long HALF = (long)BB * sX;

    const dim3 blk(256);
    unsigned short* ws = (unsigned short*)d_ws;

    // ---- big-path ws layout (shorts), total 57,056,256 shorts = 114,112,512 B
    //  0        WaE..WfahE (6 x 65536)               -> 393216
    //  393216   biases f32 (1536)                    -> 396288
    //  396288   rinv f32 (8*2304 = 18432 f)          -> 433152
    //  433152   fa                                   -> 2792448
    //  2792448  faT                                  -> 5151744
    //  5151744  gav                                  -> 7511040
    //  7511040  gah                                  -> 9870336
    //  9870336  fq                                   -> 12229632 } omidF f32
    //  12229632 fqT                                  -> 14588928 } (4718592 sh)
    //  14588928 PT (8*5308416)                       -> 57056256
    constexpr size_t WS_BIG = 114112512ull;

    if (ws_size >= WS_BIG) {
        unsigned short* WaE   = ws;
        unsigned short* WvE   = ws + 65536;
        unsigned short* WgavE = ws + 131072;
        unsigned short* WgahE = ws + 196608;
        unsigned short* WfavE = ws + 262144;
        unsigned short* WfahE = ws + 327680;
        float* biases = (float*)(ws + 393216);
        float* rinv   = (float*)(ws + 396288);
        unsigned short* fa   = ws + 433152;
        unsigned short* faT  = ws + 2792448;
        unsigned short* gav  = ws + 5151744;
        unsigned short* gah  = ws + 7511040;
        unsigned short* fq   = ws + 9870336;
        unsigned short* fqT  = ws + 12229632;
        float* omidF         = (float*)(ws + 9870336);   // overlays fq+fqT
        unsigned short* PT   = ws + 14588928;

        float* baE   = biases;
        float* bvE   = biases + 128;
        float* bgavF = biases + 256;
        float* bgahF = biases + 384;
        float* bfavF = biases + 512;
        float* bfahF = biases + 1024;

        fold_kernel<<<256, 256, 0, stream>>>(Wa, ba, ga, ta, Wv, bv, gv, tv,
                                             Wgav, bgav, Wgah, bgah, Wfav, bfav, Wfah, bfah,
                                             WaE, WvE, WgavE, WgahE, WfavE, WfahE, biases);

        // proj4: cls 0=fa(relu) 1=fv->fq(relu) 2=gav 3=gah
        proj4_kernel<<<dim3(36, 2, 32), blk, 0, stream>>>(
            WaE, WvE, WgavE, WgahE,
            baE, bvE, bgavF, bgahF,
            x, x_v, x, x,
            fa, fq, gav, gah, 3);

        transpose_kernel<<<dim3(36, 2, 8), blk, 0, stream>>>(fa, faT);
        transpose_kernel<<<dim3(36, 2, 8), blk, 0, stream>>>(fq, fqT);

        // ---- direction v -> o_v at out+HALF ----
        zerof_kernel<<<72, blk, 0, stream>>>(rinv, BB * NB);
        scoreT_kernel<<<dim3(36, 36, 8), blk, 0, stream>>>(faT, fqT, PT, rinv);
        stats_inv_kernel<<<72, blk, 0, stream>>>(rinv);
        zerof_kernel<<<1024, blk, 0, stream>>>(omidF, (int)(BB * sF));  // fq/fqT dead
        pv2_kernel<<<dim3(36, 2, 24), blk, 0, stream>>>(gav, PT, rinv, omidF);
        gemm_kernel<false,3,true,true,false><<<dim3(36,8,8), blk, 0, stream>>>(
            WfavE, 0, omidF, sF, out + HALF, sX, bfavF, x, sX, nullptr, CC, MID, NB, 1.f);

        // deferred fh projection (omidF dead after final_v)
        proj4_kernel<<<dim3(36, 2, 8), blk, 0, stream>>>(
            WvE, WvE, WvE, WvE,
            bvE, bvE, bvE, bvE,
            x_h, x_h, x_h, x_h,
            fq, fq, fq, fq, 1);
        transpose_kernel<<<dim3(36, 2, 8), blk, 0, stream>>>(fq, fqT);

        // ---- direction h -> o_h at out[0] ----
        zerof_kernel<<<72, blk, 0, stream>>>(rinv, BB * NB);
        scoreT_kernel<<<dim3(36, 36, 8), blk, 0, stream>>>(faT, fqT, PT, rinv);
        stats_inv_kernel<<<72, blk, 0, stream>>>(rinv);
        zerof_kernel<<<1024, blk, 0, stream>>>(omidF, (int)(BB * sF));  // fq/fqT dead
        pv2_kernel<<<dim3(36, 2, 24), blk, 0, stream>>>(gah, PT, rinv, omidF);
        gemm_kernel<false,3,true,true,false><<<dim3(36,8,8), blk, 0, stream>>>(
            WfahE, 0, omidF, sF, out, sX, bfahF, x, sX, nullptr, CC, MID, NB, 1.f);

        return;
    }

    // ---------------- fallback: exact Round-3 per-batch path ----------------
    constexpr size_t WS_NEED = 7280640;
    if (ws_size < WS_NEED) return;

    unsigned short* WaE   = ws;
    unsigned short* WvE   = ws + 65536;
    unsigned short* WgavE = ws + 131072;
    unsigned short* WgahE = ws + 196608;
    unsigned short* WfavE = ws + 262144;
    unsigned short* WfahE = ws + 327680;
    float* biases = (float*)(ws + 393216);
    unsigned short* fab  = ws + 396288;
    unsigned short* qb   = ws + 691200;
    unsigned short* gb   = ws + 986112;
    unsigned short* omid = ws + 1281024;
    unsigned short* Pb = (unsigned short*)d_out;

    float* baE   = biases;
    float* bvE   = biases + 128;
    float* bgavF = biases + 256;
    float* bgahF = biases + 384;
    float* bfavF = biases + 512;
    float* bfahF = biases + 1024;

    fold_kernel<<<256, 256, 0, stream>>>(Wa, ba, ga, ta, Wv, bv, gv, tv,
                                         Wgav, bgav, Wgah, bgah, Wfav, bfav, Wfah, bfah,
                                         WaE, WvE, WgavE, WgahE, WfavE, WfahE, biases);

    for (int b = 0; b < BB; b++) {
        const float* xb  = x   + (long)b * sX;
        const float* xqb = x_v + (long)b * sX;
        gemm_kernel<false,1,true,false,false><<<dim3(36,2,1), blk, 0, stream>>>(WaE,   0, xb,  0, fab, 0, baE,   nullptr, 0, nullptr, MID, CC, NB, 1.f);
        gemm_kernel<false,1,true,false,false><<<dim3(36,2,1), blk, 0, stream>>>(WvE,   0, xqb, 0, qb,  0, bvE,   nullptr, 0, nullptr, MID, CC, NB, 1.f);
        gemm_kernel<false,2,true,false,false><<<dim3(36,2,1), blk, 0, stream>>>(WgavE, 0, xb,  0, gb,  0, bgavF, nullptr, 0, nullptr, MID, CC, NB, 1.f);
        gemm_kernel<true,0,false,false,false><<<dim3(36,36,1), blk, 0, stream>>>(qb, 0, fab, 0, Pb, 0, nullptr, nullptr, 0, nullptr, NB, MID, NB, ATT_SCALE);
        softmax_rows<<<NB / 4, blk, 0, stream>>>(Pb);
        gemm_kernel<false,0,false,false,false><<<dim3(36,2,1), blk, 0, stream>>>(gb, 0, Pb, 0, omid + (long)b * sF, 0, nullptr, nullptr, 0, nullptr, MID, NB, NB, 1.f);
    }
    gemm_kernel<false,3,false,true,false><<<dim3(36,8,8), blk, 0, stream>>>(WfavE, 0, omid, sF, out + HALF, sX, bfavF, x, sX, nullptr, CC, MID, NB, 1.f);

    for (int b = 0; b < BB; b++) {
        const float* xb  = x   + (long)b * sX;
        const float* xqb = x_h + (long)b * sX;
        gemm_kernel<false,1,true,false,false><<<dim3(36,2,1), blk, 0, stream>>>(WaE,   0, xb,  0, fab, 0, baE,   nullptr, 0, nullptr, MID, CC, NB, 1.f);
        gemm_kernel<false,1,true,false,false><<<dim3(36,2,1), blk, 0, stream>>>(WvE,   0, xqb, 0, qb,  0, bvE,   nullptr, 0, nullptr, MID, CC, NB, 1.f);
        gemm_kernel<false,2,true,false,false><<<dim3(36,2,1), blk, 0, stream>>>(WgahE, 0, xb,  0, gb,  0, bgahF, nullptr, 0, nullptr, MID, CC, NB, 1.f);
        gemm_kernel<true,0,false,false,false><<<dim3(36,36,1), blk, 0, stream>>>(qb, 0, fab, 0, Pb, 0, nullptr, nullptr, 0, nullptr, NB, MID, NB, ATT_SCALE);
        softmax_rows<<<NB / 4, blk, 0, stream>>>(Pb);
        gemm_kernel<false,0,false,false,false><<<dim3(36,2,1), blk, 0, stream>>>(gb, 0, Pb, 0, omid + (long)b * sF, 0, nullptr, nullptr, 0, nullptr, MID, NB, NB, 1.f);
    }
    gemm_kernel<false,3,false,true,false><<<dim3(36,8,8), blk, 0, stream>>>(WfahE, 0, omid, sF, out, sX, bfahF, x, sX, nullptr, CC, MID, NB, 1.f);

    (void)in_sizes; (void)n_in; (void)out_size;
}